// Round 1
// baseline (4443.152 us; speedup 1.0000x reference)
//
#include <hip/hip_runtime.h>

typedef __bf16 bf16;
typedef __bf16 bf16x8 __attribute__((ext_vector_type(8)));
typedef __bf16 bf16x4 __attribute__((ext_vector_type(4)));
typedef float  f32x4  __attribute__((ext_vector_type(4)));

#define DEV __device__ __forceinline__

// async global->LDS, 16B per lane; lds dest must be wave-uniform base (HW adds lane*16)
DEV void gload_lds16(const bf16* g, bf16* l) {
    __builtin_amdgcn_global_load_lds(
        (__attribute__((address_space(1))) void*)g,
        (__attribute__((address_space(3))) void*)l, 16, 0, 0);
}

// ---------------------------------------------------------------------------
// GEMM: C[m,n] = sum_k A[m,k]*B[n,k].  A:[M,K] bf16 row-major, B:[N,K] bf16
// row-major. 128x128 tile, BK=32, 256 thr (4 waves 2x2), wave = 64x64 (4x4
// frags of 16x16x32). Double-buffered LDS + global_load_lds (m97 structure).
// ---------------------------------------------------------------------------
enum { M_QKV, M_SCORES, M_PV, M_BIAS, M_RESID, M_GELU, M_OUT };

template<int MODE>
__global__ __launch_bounds__(256)
void gemm_k(const bf16* __restrict__ A, const bf16* __restrict__ B,
            int M, int N, int K,
            long long batchA, long long batchB, long long batchC,
            const float* __restrict__ bias,
            bf16* __restrict__ Cb, float* __restrict__ Cf,
            bf16* __restrict__ qp, bf16* __restrict__ kp, bf16* __restrict__ vp)
{
    const int bm = blockIdx.x, bn = blockIdx.y, bz = blockIdx.z;
    if (MODE == M_SCORES && bn > bm) return;          // fully-masked tile
    int kTiles = K >> 5;
    if (MODE == M_PV) {                               // P[:,k]==0 for k>row
        int lim = (bm + 1) * 4;
        if (lim < kTiles) kTiles = lim;
    }

    const int tid = threadIdx.x, wid = tid >> 6, lane = tid & 63;
    const bf16* Ab = A + (long long)bz * batchA + (long long)bm * 128 * K;
    const bf16* Bb = B + (long long)bz * batchB + (long long)bn * 128 * K;

    __shared__ __align__(16) bf16 sA[2][4096];
    __shared__ __align__(16) bf16 sB[2][4096];

    const int srow = wid * 16 + (lane >> 2);          // 0..63 within 64-row half
    const int scol = (lane & 3) * 8;
    const long long aoff = (long long)srow * K + scol;

    auto stage = [&](int buf, int kt) {
        const bf16* ga = Ab + (long long)kt * 32;
        const bf16* gb = Bb + (long long)kt * 32;
        gload_lds16(ga + aoff,            &sA[buf][(wid * 16) * 32]);
        gload_lds16(ga + aoff + 64LL * K, &sA[buf][(64 + wid * 16) * 32]);
        gload_lds16(gb + aoff,            &sB[buf][(wid * 16) * 32]);
        gload_lds16(gb + aoff + 64LL * K, &sB[buf][(64 + wid * 16) * 32]);
    };

    f32x4 acc[4][4];
#pragma unroll
    for (int m = 0; m < 4; ++m)
#pragma unroll
        for (int n = 0; n < 4; ++n) acc[m][n] = (f32x4){0.f, 0.f, 0.f, 0.f};

    stage(0, 0);
    __syncthreads();

    const int wr = wid >> 1, wc = wid & 1;
    const int arow = wr * 64 + (lane & 15);
    const int brow = wc * 64 + (lane & 15);
    const int koff = (lane >> 4) * 8;

    for (int kt = 0; kt < kTiles; ++kt) {
        const int cur = kt & 1;
        if (kt + 1 < kTiles) stage(cur ^ 1, kt + 1);
        bf16x8 af[4], bfr[4];
#pragma unroll
        for (int m = 0; m < 4; ++m)
            af[m] = *(const bf16x8*)&sA[cur][(arow + m * 16) * 32 + koff];
#pragma unroll
        for (int n = 0; n < 4; ++n)
            bfr[n] = *(const bf16x8*)&sB[cur][(brow + n * 16) * 32 + koff];
#pragma unroll
        for (int m = 0; m < 4; ++m)
#pragma unroll
            for (int n = 0; n < 4; ++n)
                acc[m][n] = __builtin_amdgcn_mfma_f32_16x16x32_bf16(af[m], bfr[n], acc[m][n], 0, 0, 0);
        __syncthreads();
    }

    // C/D layout: col = lane&15, row = (lane>>4)*4 + r   [learn_hip m89]
    const int cr0 = bm * 128 + wr * 64 + (lane >> 4) * 4;
    const int cc0 = bn * 128 + wc * 64 + (lane & 15);
#pragma unroll
    for (int m = 0; m < 4; ++m) {
#pragma unroll
        for (int n = 0; n < 4; ++n) {
            const int col = cc0 + n * 16;
#pragma unroll
            for (int r = 0; r < 4; ++r) {
                const int row = cr0 + m * 16 + r;
                float v = acc[m][n][r];
                if (MODE == M_QKV) {
                    v += bias[col];
                    int hd = col / 192, rr = col % 192;
                    int b = row >> 10, s = row & 1023;
                    if (rr < 64)
                        qp[(long long)row * 768 + hd * 64 + rr] = (bf16)(v * 0.03608439182435161f);
                    else if (rr < 128)
                        kp[(long long)row * 768 + hd * 64 + (rr - 64)] = (bf16)v;
                    else // v transposed: vT[b, d, s]
                        vp[((long long)b * 768 + hd * 64 + (rr - 128)) * 1024 + s] = (bf16)v;
                } else if (MODE == M_SCORES || MODE == M_PV) {
                    Cb[(long long)bz * batchC + (long long)row * N + col] = (bf16)v;
                } else if (MODE == M_BIAS) {
                    Cb[(long long)row * N + col] = (bf16)(v + bias[col]);
                } else if (MODE == M_RESID) {
                    long long idx = (long long)row * N + col;
                    Cf[idx] += v + bias[col];
                } else if (MODE == M_GELU) {
                    float xg = v + bias[col];
                    Cb[(long long)row * N + col] = (bf16)(xg / (1.f + __expf(-1.702f * xg)));
                } else { // M_OUT
                    Cf[(long long)row * N + col] = v + bias[col];
                }
            }
        }
    }
}

// ---------------------------------------------------------------------------
__global__ __launch_bounds__(256)
void cvt_bf16_k(const float* __restrict__ in, bf16* __restrict__ out, int n4)
{
    int i = blockIdx.x * 256 + threadIdx.x;
    if (i >= n4) return;
    float4 f = ((const float4*)in)[i];
    bf16x4 o = { (bf16)f.x, (bf16)f.y, (bf16)f.z, (bf16)f.w };
    ((bf16x4*)out)[i] = o;
}

// scale[l,b,d] = sum_c label[b,c]*sw[l,d,c]; bias likewise. total = L*8*768
__global__ __launch_bounds__(256)
void cond_proj_k(const float* __restrict__ label, const float* __restrict__ sw,
                 const float* __restrict__ bw, float* __restrict__ scale,
                 float* __restrict__ bias, int total)
{
    int idx = blockIdx.x * 256 + threadIdx.x;
    if (idx >= total) return;
    int l = idx / 6144;
    int rem = idx - l * 6144;
    int b = rem / 768, d = rem - (rem / 768) * 768;
    const float* lab = label + b * 17;
    const float* swp = sw + ((long long)l * 768 + d) * 17;
    const float* bwp = bw + ((long long)l * 768 + d) * 17;
    float s = 0.f, bb = 0.f;
#pragma unroll
    for (int c = 0; c < 17; ++c) { float lv = lab[c]; s += lv * swp[c]; bb += lv * bwp[c]; }
    scale[idx] = s;
    bias[idx]  = bb;
}

// dense_in + SOS right-shift + broadcast position biases -> h fp32
__global__ __launch_bounds__(256)
void embed_k(const float* __restrict__ x, const float* __restrict__ w,
             const float* __restrict__ wb, const float* __restrict__ sos,
             const float* __restrict__ p0, const float* __restrict__ p1,
             const float* __restrict__ p2, float* __restrict__ h)
{
    const int s = blockIdx.x, b = blockIdx.y;
    __shared__ __align__(16) float xr[64];
    if (s > 0 && threadIdx.x < 64)
        xr[threadIdx.x] = x[((long long)b * 1024 + (s - 1)) * 64 + threadIdx.x];
    __syncthreads();
    const int i0 = s >> 8, i1 = (s >> 4) & 15, i2 = s & 15;
#pragma unroll
    for (int j = 0; j < 3; ++j) {
        const int d = j * 256 + threadIdx.x;
        float v;
        if (s == 0) {
            v = sos[d];
        } else {
            const float4* wr4 = (const float4*)(w + (long long)d * 64);
            const float4* xr4 = (const float4*)xr;
            float acc = 0.f;
#pragma unroll
            for (int t = 0; t < 16; ++t) {
                float4 wv = wr4[t], xv = xr4[t];
                acc += wv.x * xv.x + wv.y * xv.y + wv.z * xv.z + wv.w * xv.w;
            }
            v = wb[d] + acc;
        }
        float pbv = (d < 256) ? p0[i0 * 256 + d]
                  : (d < 512) ? p1[i1 * 256 + (d - 256)]
                              : p2[i2 * 256 + (d - 512)];
        h[((long long)b * 1024 + s) * 768 + d] = v + pbv;
    }
}

// conditional LayerNorm: out = (h-mean)*rsqrt(var+eps)*(1+scale[b,:]) + bias[b,:], bf16 out
__global__ __launch_bounds__(256)
void cond_ln_k(const float* __restrict__ h, const float* __restrict__ scale,
               const float* __restrict__ bias, bf16* __restrict__ out)
{
    const long long row = (long long)blockIdx.y * 1024 + blockIdx.x;
    const int b = blockIdx.y;
    const float* hr = h + row * 768;
    float v[3], sum = 0.f, sq = 0.f;
#pragma unroll
    for (int j = 0; j < 3; ++j) {
        v[j] = hr[j * 256 + threadIdx.x];
        sum += v[j]; sq += v[j] * v[j];
    }
    __shared__ float sm[8];
#pragma unroll
    for (int o = 32; o; o >>= 1) { sum += __shfl_down(sum, o); sq += __shfl_down(sq, o); }
    const int wid = threadIdx.x >> 6;
    if ((threadIdx.x & 63) == 0) { sm[wid] = sum; sm[4 + wid] = sq; }
    __syncthreads();
    sum = sm[0] + sm[1] + sm[2] + sm[3];
    sq  = sm[4] + sm[5] + sm[6] + sm[7];
    const float mean = sum * (1.f / 768.f);
    const float var  = sq * (1.f / 768.f) - mean * mean;
    const float rs   = rsqrtf(var + 1e-6f);
    const float* sc = scale + (long long)b * 768;
    const float* bi = bias  + (long long)b * 768;
    bf16* orow = out + row * 768;
#pragma unroll
    for (int j = 0; j < 3; ++j) {
        const int d = j * 256 + threadIdx.x;
        orow[d] = (bf16)((v[j] - mean) * rs * (1.f + sc[d]) + bi[d]);
    }
}

// in-place causal softmax over row i (valid cols 0..i), zeros beyond
__global__ __launch_bounds__(256)
void softmax_k(bf16* __restrict__ P)
{
    const int i = blockIdx.x, b = blockIdx.y;
    bf16* row = P + ((long long)b * 1024 + i) * 1024;
    const int len = i + 1;
    float v[4], mx = -1e30f;
#pragma unroll
    for (int j = 0; j < 4; ++j) {
        int c = j * 256 + threadIdx.x;
        v[j] = (c < len) ? (float)row[c] : -1e30f;
        mx = fmaxf(mx, v[j]);
    }
    __shared__ float sm[8];
#pragma unroll
    for (int o = 32; o; o >>= 1) mx = fmaxf(mx, __shfl_down(mx, o));
    const int wid = threadIdx.x >> 6;
    if ((threadIdx.x & 63) == 0) sm[wid] = mx;
    __syncthreads();
    mx = fmaxf(fmaxf(sm[0], sm[1]), fmaxf(sm[2], sm[3]));
    float s = 0.f;
#pragma unroll
    for (int j = 0; j < 4; ++j) {
        v[j] = __expf(v[j] - mx);
        s += ((j * 256 + threadIdx.x) < len) ? v[j] : 0.f;
    }
#pragma unroll
    for (int o = 32; o; o >>= 1) s += __shfl_down(s, o);
    if ((threadIdx.x & 63) == 0) sm[4 + wid] = s;
    __syncthreads();
    s = sm[4] + sm[5] + sm[6] + sm[7];
    const float inv = 1.f / s;
#pragma unroll
    for (int j = 0; j < 4; ++j) {
        int c = j * 256 + threadIdx.x;
        row[c] = (c < len) ? (bf16)(v[j] * inv) : (bf16)0.f;
    }
}

__global__ __launch_bounds__(256)
void fill_k(float* o, int n, float v)
{
    int i = blockIdx.x * 256 + threadIdx.x;
    if (i < n) o[i] = v;
}

// ---------------------------------------------------------------------------
extern "C" void kernel_launch(void* const* d_in, const int* in_sizes, int n_in,
                              void* d_out, int out_size, void* d_ws, size_t ws_size,
                              hipStream_t stream)
{
    (void)in_sizes; (void)n_in;
    const float* x     = (const float*)d_in[0];
    // d_in[1] = mask: always causal tril, handled structurally
    const float* label = (const float*)d_in[2];
    const float* dw    = (const float*)d_in[3];
    const float* db    = (const float*)d_in[4];
    const float* sos   = (const float*)d_in[5];
    const float* p0    = (const float*)d_in[6];
    const float* p1    = (const float*)d_in[7];
    const float* p2    = (const float*)d_in[8];
    const float* ln1sw = (const float*)d_in[9];
    const float* ln1bw = (const float*)d_in[10];
    const float* qkvw  = (const float*)d_in[11];
    const float* qkvb  = (const float*)d_in[12];
    const float* ao1w  = (const float*)d_in[13];
    const float* ao1b  = (const float*)d_in[14];
    const float* ao2w  = (const float*)d_in[15];
    const float* ao2b  = (const float*)d_in[16];
    const float* ln2sw = (const float*)d_in[17];
    const float* ln2bw = (const float*)d_in[18];
    const float* m1w   = (const float*)d_in[19];
    const float* m1b   = (const float*)d_in[20];
    const float* m2w   = (const float*)d_in[21];
    const float* m2b   = (const float*)d_in[22];
    const float* lnfsw = (const float*)d_in[23];
    const float* lnfbw = (const float*)d_in[24];
    const float* outw  = (const float*)d_in[25];
    const float* outb  = (const float*)d_in[26];
    float* out = (float*)d_out;

    char* p = (char*)d_ws;
    auto alloc = [&](size_t bytes) { void* r = (void*)p; p += (bytes + 255) & ~(size_t)255; return r; };
    float* h    = (float*)alloc(8192LL * 768 * 4);
    bf16*  hn   = (bf16*) alloc(8192LL * 768 * 2);
    bf16*  q    = (bf16*) alloc(8192LL * 768 * 2);
    bf16*  kbuf = (bf16*) alloc(8192LL * 768 * 2);
    bf16*  vT   = (bf16*) alloc(8192LL * 768 * 2);   // [B,768,1024]
    bf16*  P    = (bf16*) alloc(8LL * 1024 * 1024 * 2);
    bf16*  attn = (bf16*) alloc(8192LL * 768 * 2);
    bf16*  o1o  = (bf16*) alloc(8192LL * 768 * 2);
    bf16*  mb   = (bf16*) alloc(8192LL * 3072 * 2);
    bf16*  wqkv = (bf16*) alloc(2304LL * 768 * 2);
    bf16*  wo1  = (bf16*) alloc(768LL * 768 * 2);
    bf16*  wo2  = (bf16*) alloc(768LL * 768 * 2);
    bf16*  wm1  = (bf16*) alloc(3072LL * 768 * 2);
    bf16*  wm2  = (bf16*) alloc(3072LL * 768 * 2);
    bf16*  wout = (bf16*) alloc(1024LL * 768 * 2);
    float* s1   = (float*)alloc(12LL * 8 * 768 * 4);
    float* b1   = (float*)alloc(12LL * 8 * 768 * 4);
    float* s2   = (float*)alloc(12LL * 8 * 768 * 4);
    float* b2   = (float*)alloc(12LL * 8 * 768 * 4);
    float* sf   = (float*)alloc(8LL * 768 * 4);
    float* bfb  = (float*)alloc(8LL * 768 * 4);

    size_t needed = (size_t)(p - (char*)d_ws);
    if (needed > ws_size) {  // signal ws-too-small distinctly (absmax ~1e9)
        fill_k<<<(out_size + 255) / 256, 256, 0, stream>>>(out, out_size, 1e9f);
        return;
    }

    // --- one-time precompute ---
    cvt_bf16_k<<<1024 * 768 / 4 / 256, 256, 0, stream>>>(outw, wout, 1024 * 768 / 4);
    cond_proj_k<<<(12 * 8 * 768 + 255) / 256, 256, 0, stream>>>(label, ln1sw, ln1bw, s1, b1, 12 * 8 * 768);
    cond_proj_k<<<(12 * 8 * 768 + 255) / 256, 256, 0, stream>>>(label, ln2sw, ln2bw, s2, b2, 12 * 8 * 768);
    cond_proj_k<<<(8 * 768 + 255) / 256, 256, 0, stream>>>(label, lnfsw, lnfbw, sf, bfb, 8 * 768);
    embed_k<<<dim3(1024, 8), 256, 0, stream>>>(x, dw, db, sos, p0, p1, p2, h);

    for (int l = 0; l < 12; ++l) {
        cvt_bf16_k<<<2304 * 768 / 4 / 256, 256, 0, stream>>>(qkvw + (long long)l * 2304 * 768, wqkv, 2304 * 768 / 4);
        cvt_bf16_k<<< 768 * 768 / 4 / 256, 256, 0, stream>>>(ao1w + (long long)l * 768 * 768,  wo1,  768 * 768 / 4);
        cvt_bf16_k<<< 768 * 768 / 4 / 256, 256, 0, stream>>>(ao2w + (long long)l * 768 * 768,  wo2,  768 * 768 / 4);
        cvt_bf16_k<<<3072 * 768 / 4 / 256, 256, 0, stream>>>(m1w  + (long long)l * 3072 * 768, wm1,  3072 * 768 / 4);
        cvt_bf16_k<<<3072 * 768 / 4 / 256, 256, 0, stream>>>(m2w  + (long long)l * 768 * 3072, wm2,  3072 * 768 / 4);

        cond_ln_k<<<dim3(1024, 8), 256, 0, stream>>>(h, s1 + (long long)l * 6144, b1 + (long long)l * 6144, hn);

        gemm_k<M_QKV><<<dim3(64, 18, 1), 256, 0, stream>>>(
            hn, wqkv, 8192, 2304, 768, 0, 0, 0,
            qkvb + (long long)l * 2304, nullptr, nullptr, q, kbuf, vT);

        gemm_k<M_SCORES><<<dim3(8, 8, 8), 256, 0, stream>>>(
            q, kbuf, 1024, 1024, 768, 1024LL * 768, 1024LL * 768, 1024LL * 1024,
            nullptr, P, nullptr, nullptr, nullptr, nullptr);

        softmax_k<<<dim3(1024, 8), 256, 0, stream>>>(P);

        gemm_k<M_PV><<<dim3(8, 6, 8), 256, 0, stream>>>(
            P, vT, 1024, 768, 1024, 1024LL * 1024, 768LL * 1024, 1024LL * 768,
            nullptr, attn, nullptr, nullptr, nullptr, nullptr);

        gemm_k<M_BIAS><<<dim3(64, 6, 1), 256, 0, stream>>>(
            attn, wo1, 8192, 768, 768, 0, 0, 0,
            ao1b + (long long)l * 768, o1o, nullptr, nullptr, nullptr, nullptr);

        gemm_k<M_RESID><<<dim3(64, 6, 1), 256, 0, stream>>>(
            o1o, wo2, 8192, 768, 768, 0, 0, 0,
            ao2b + (long long)l * 768, nullptr, h, nullptr, nullptr, nullptr);

        cond_ln_k<<<dim3(1024, 8), 256, 0, stream>>>(h, s2 + (long long)l * 6144, b2 + (long long)l * 6144, hn);

        gemm_k<M_GELU><<<dim3(64, 24, 1), 256, 0, stream>>>(
            hn, wm1, 8192, 3072, 768, 0, 0, 0,
            m1b + (long long)l * 3072, mb, nullptr, nullptr, nullptr, nullptr);

        gemm_k<M_RESID><<<dim3(64, 6, 1), 256, 0, stream>>>(
            mb, wm2, 8192, 768, 3072, 0, 0, 0,
            m2b + (long long)l * 768, nullptr, h, nullptr, nullptr, nullptr);
    }

    cond_ln_k<<<dim3(1024, 8), 256, 0, stream>>>(h, sf, bfb, hn);
    gemm_k<M_OUT><<<dim3(64, 8, 1), 256, 0, stream>>>(
        hn, wout, 8192, 1024, 768, 0, 0, 0,
        outb, nullptr, out, nullptr, nullptr, nullptr);
}